// Round 13
// baseline (242.582 us; speedup 1.0000x reference)
//
#include <hip/hip_runtime.h>
#include <hip/hip_bf16.h>

// 2-layer GIN, pull-mode aggregation over COLUMN-SLAB bf16 layout.
//   aggb = bf16( f32(hb[n]) + sum f32(hb[src]) );  h' = relu(agg @ W + b)
// R13: feature matrix stored as 4 slabs of 16 columns (3.2 MB each — fits a
// single XCD's 4 MB L2). Aggregation = 4 sequential passes (pass-major block
// order in ONE dispatch); each pass's gathers are L2-resident after warm-up,
// turning L3 random misses into streaming line fills.
// Requires n_nodes <= 131072 (18-bit src pack, 256-bucket scans).

#define D 64
#define ROWS_PER_BLOCK 32
#define CHSZ 4096      // edges per chunk (k1/k3)
#define NPBS 512       // nodes per super-bucket
#define SBSHIFT 9      // log2(NPBS)
#define MAXNBS 256     // static cap on #super-buckets (n_nodes <= 131072)
#define MAXNCH 512     // static cap on #chunks in k2c (n_edges <= 2.1M)
#define NSLAB 4        // column slabs (16 cols = 32 B bf16 each)

typedef unsigned short ushort_t;

__device__ inline unsigned short f2bf(float f) {   // RNE round to bf16
    unsigned u = __float_as_uint(f);
    return (unsigned short)((u + 0x7fff + ((u >> 16) & 1)) >> 16);
}

// acc[0..7] += 8 bf16 unpacked from one uint4
__device__ inline void acc8(float* acc, uint4 v) {
    acc[0] += __uint_as_float(v.x << 16);
    acc[1] += __uint_as_float(v.x & 0xffff0000u);
    acc[2] += __uint_as_float(v.y << 16);
    acc[3] += __uint_as_float(v.y & 0xffff0000u);
    acc[4] += __uint_as_float(v.z << 16);
    acc[5] += __uint_as_float(v.z & 0xffff0000u);
    acc[6] += __uint_as_float(v.w << 16);
    acc[7] += __uint_as_float(v.w & 0xffff0000u);
}

// 8 floats from one uint4 of packed bf16
__device__ inline void unpack8(float* v, uint4 u) {
    v[0] = __uint_as_float(u.x << 16); v[1] = __uint_as_float(u.x & 0xffff0000u);
    v[2] = __uint_as_float(u.y << 16); v[3] = __uint_as_float(u.y & 0xffff0000u);
    v[4] = __uint_as_float(u.z << 16); v[5] = __uint_as_float(u.z & 0xffff0000u);
    v[6] = __uint_as_float(u.w << 16); v[7] = __uint_as_float(u.w & 0xffff0000u);
}

// ---------------- CSR build ----------------

// fp32 -> bf16 conversion into SLAB layout; block 0 zeros bucket totals.
// Slab p (p = col/16) is a contiguous [n_nodes][16] bf16 array.
__global__ __launch_bounds__(256) void to_bf16z(const float4* __restrict__ in,
                                                uint2* __restrict__ outs, int n4,
                                                int* __restrict__ total, int nbs,
                                                int n_nodes) {
    int i = blockIdx.x * 256 + threadIdx.x;
    if (blockIdx.x == 0)
        for (int j = threadIdx.x; j < nbs; j += 256) total[j] = 0;
    if (i >= n4) return;
    float4 v = in[i];
    int n = i >> 4;
    int q = i & 15;            // float4 index within the 64-col row
    int p = q >> 2;            // slab
    int u2i = q & 3;           // uint2 within the 16-col slab row
    outs[(size_t)p * n_nodes * 4 + n * 4 + u2i] =
        make_uint2((unsigned)f2bf(v.x) | ((unsigned)f2bf(v.y) << 16),
                   (unsigned)f2bf(v.z) | ((unsigned)f2bf(v.w) << 16));
}

// Per-chunk LDS histogram over super-buckets; accumulates per-bucket totals.
__global__ __launch_bounds__(512) void k1_hist(const int* __restrict__ dst,
                                               int* __restrict__ hist,
                                               int* __restrict__ total,
                                               int n_edges, int nch, int nbs) {
    __shared__ int lh[MAXNBS];
    for (int i = threadIdx.x; i < nbs; i += 512) lh[i] = 0;
    __syncthreads();
    int base = blockIdx.x * CHSZ;
    int lim = min(CHSZ, n_edges - base);
    for (int k = threadIdx.x; k < lim; k += 512)
        atomicAdd(&lh[dst[base + k] >> SBSHIFT], 1);
    __syncthreads();
    for (int i = threadIdx.x; i < nbs; i += 512) {
        int v = lh[i];
        hist[i * nch + blockIdx.x] = v;   // bucket-major
        if (v) atomicAdd(&total[i], v);
    }
}

// One block per bucket: totals prefix (k2b folded) + row scan, in place.
__global__ __launch_bounds__(256) void k2c_rowscan(int* __restrict__ hist,
                                                   const int* __restrict__ total,
                                                   int* __restrict__ sstart,
                                                   int nch, int nbs, int n_edges) {
    __shared__ int tt[256];
    __shared__ int t[MAXNCH];
    int b = blockIdx.x;
    int tid = threadIdx.x;

    tt[tid] = (tid < nbs) ? total[tid] : 0;
    __syncthreads();
    for (int off = 1; off < 256; off <<= 1) {
        int v = (tid >= off) ? tt[tid - off] : 0;
        __syncthreads();
        tt[tid] += v;
        __syncthreads();
    }
    int base = (b == 0) ? 0 : tt[b - 1];
    if (tid == 0) {
        sstart[b] = base;
        if (b == 0) sstart[nbs] = n_edges;
    }

    int* row = hist + (size_t)b * nch;
    int nround = (nch + 255) & ~255;
    for (int i = tid; i < nround; i += 256) t[i] = (i < nch) ? row[i] : 0;
    __syncthreads();
    for (int off = 1; off < nround; off <<= 1) {
        int v[MAXNCH / 256];
        for (int i = tid, j = 0; i < nround; i += 256, ++j)
            v[j] = (i >= off) ? t[i - off] : 0;
        __syncthreads();
        for (int i = tid, j = 0; i < nround; i += 256, ++j) t[i] += v[j];
        __syncthreads();
    }
    for (int i = tid; i < nch; i += 256)
        row[i] = base + ((i == 0) ? 0 : t[i - 1]);
}

__global__ __launch_bounds__(512) void k3_scatter(const int* __restrict__ src,
                                                  const int* __restrict__ dst,
                                                  const int* __restrict__ hist,
                                                  unsigned* __restrict__ tmp,
                                                  int n_edges, int nch, int nbs) {
    __shared__ int lcur[MAXNBS];
    int c = blockIdx.x;
    for (int i = threadIdx.x; i < nbs; i += 512) lcur[i] = hist[i * nch + c];
    __syncthreads();
    int base = c * CHSZ;
    int lim = min(CHSZ, n_edges - base);
    for (int k = threadIdx.x; k < lim; k += 512) {
        int d = dst[base + k];
        int s = src[base + k];
        int pos = atomicAdd(&lcur[d >> SBSHIFT], 1);
        tmp[pos] = ((unsigned)(d & (NPBS - 1)) << 18) | (unsigned)s;
    }
}

// One WG (512 thr) per super-bucket: node-level counting sort.
// esrc PRE-SCALED: value = src*2 (uint4 index of the row base WITHIN a slab).
__global__ __launch_bounds__(512) void k4_fine(const unsigned* __restrict__ tmp,
                                               const int* __restrict__ sstart,
                                               int* __restrict__ esrc,
                                               int* __restrict__ offs,
                                               int n_nodes) {
    __shared__ int lcnt[NPBS];
    __shared__ int lcur[NPBS];
    __shared__ int tsum[256];

    int b = blockIdx.x;
    int tid = threadIdx.x;
    int base = sstart[b];
    int cnt = sstart[b + 1] - base;

    lcnt[tid] = 0;
    __syncthreads();

    for (int i = tid; i < cnt; i += 512)
        atomicAdd(&lcnt[tmp[base + i] >> 18], 1);
    __syncthreads();

    int a0 = 0, a1 = 0;
    if (tid < 256) {
        a0 = lcnt[2 * tid];
        a1 = lcnt[2 * tid + 1];
        tsum[tid] = a0 + a1;
    }
    __syncthreads();
    for (int off = 1; off < 256; off <<= 1) {
        int v = 0;
        if (tid < 256 && tid >= off) v = tsum[tid - off];
        __syncthreads();
        if (tid < 256) tsum[tid] += v;
        __syncthreads();
    }
    if (tid < 256) {
        int ex = (tid == 0) ? 0 : tsum[tid - 1];
        lcur[2 * tid] = ex;
        lcur[2 * tid + 1] = ex + a0;
        int node = b * NPBS + 2 * tid;
        if (node <= n_nodes) offs[node] = base + ex;
        if (node + 1 <= n_nodes) offs[node + 1] = base + ex + a0;
    }
    __syncthreads();

    for (int i = tid; i < cnt; i += 512) {
        unsigned p = tmp[base + i];
        int pos = atomicAdd(&lcur[p >> 18], 1);
        esrc[base + pos] = (int)((p & 0x3FFFFu) << 1);   // src*2
    }
}

// ---------------- per-layer kernels ----------------

// Slab-pass pull aggregation. One dispatch = NSLAB passes, pass-major block
// order: pass p only touches slab p (3.2 MB -> per-XCD L2 resident).
// 2 lanes/node; lane c owns one uint4 (8 bf16) of the 16-col slab row.
// Edge loop unrolled 8x. acc starts at slab[n] (self term, eps=0).
__global__ __launch_bounds__(256) void gin_agg_slab(const uint4* __restrict__ hbs,
                                                    const int* __restrict__ offs,
                                                    const int* __restrict__ esrc,
                                                    uint4* __restrict__ abs_,
                                                    int n_nodes, int nblk) {
    int pass = blockIdx.x / nblk;
    int t = (blockIdx.x - pass * nblk) * 256 + threadIdx.x;
    int n = t >> 1;
    if (n >= n_nodes) return;
    int c = t & 1;
    const uint4* slab = hbs + (size_t)pass * n_nodes * 2;

    float acc[8];
#pragma unroll
    for (int j = 0; j < 8; ++j) acc[j] = 0.0f;
    acc8(acc, slab[n * 2 + c]);   // self term

    int i = offs[n];
    int end = offs[n + 1];

    for (; i + 8 <= end; i += 8) {
        uint4 v[8];
#pragma unroll
        for (int j = 0; j < 8; ++j)
            v[j] = slab[(unsigned)esrc[i + j] + c];
#pragma unroll
        for (int j = 0; j < 8; ++j) acc8(acc, v[j]);
    }
    if (i + 4 <= end) {
        uint4 v[4];
#pragma unroll
        for (int j = 0; j < 4; ++j)
            v[j] = slab[(unsigned)esrc[i + j] + c];
#pragma unroll
        for (int j = 0; j < 4; ++j) acc8(acc, v[j]);
        i += 4;
    }
    for (; i < end; ++i)
        acc8(acc, slab[(unsigned)esrc[i] + c]);

    uint4 o;
    o.x = (unsigned)f2bf(acc[0]) | ((unsigned)f2bf(acc[1]) << 16);
    o.y = (unsigned)f2bf(acc[2]) | ((unsigned)f2bf(acc[3]) << 16);
    o.z = (unsigned)f2bf(acc[4]) | ((unsigned)f2bf(acc[5]) << 16);
    o.w = (unsigned)f2bf(acc[6]) | ((unsigned)f2bf(acc[7]) << 16);
    abs_[(size_t)pass * n_nodes * 2 + n * 2 + c] = o;
}

// out = relu(hs @ W + b); hs is bf16 in SLAB layout, staged to fp32 LDS.
// BF16OUT: store bf16 in SLAB layout (next layer's gather input);
// else fp32 row-major (final output).
#define RSTRIDE (D + 4)   // padded LDS row stride (bank-spread)
template <bool BF16OUT>
__global__ __launch_bounds__(256) void gin_mlp(const uint4* __restrict__ hss,
                                               const float* __restrict__ W,
                                               const float* __restrict__ b,
                                               void* __restrict__ out_,
                                               int n_nodes) {
    __shared__ float Wl[D * D];
    __shared__ float bl[D];
    __shared__ float rows[ROWS_PER_BLOCK * RSTRIDE];

    int tid = threadIdx.x;

    const float4* W4 = (const float4*)W;
    float4* Wl4 = (float4*)Wl;
#pragma unroll
    for (int i = 0; i < 4; ++i) Wl4[tid + 256 * i] = W4[tid + 256 * i];
    if (tid < D / 4) ((float4*)bl)[tid] = ((const float4*)b)[tid];

    // stage 32 slab-layout bf16 rows -> fp32 LDS
    // tid -> (r = tid>>3, p = (tid>>1)&3, half = tid&1)
    size_t row0 = (size_t)blockIdx.x * ROWS_PER_BLOCK;
    {
        int r = tid >> 3;
        int p = (tid >> 1) & 3;
        int half = tid & 1;
        uint4 u = hss[(size_t)p * n_nodes * 2 + (row0 + r) * 2 + half];
        float v[8];
        unpack8(v, u);
        float* dstp = rows + r * RSTRIDE + p * 16 + half * 8;
#pragma unroll
        for (int j = 0; j < 8; ++j) dstp[j] = v[j];
    }
    __syncthreads();

    int lane = tid & 63;
    int w = tid >> 6;

    float acc[8];
#pragma unroll
    for (int r = 0; r < 8; ++r) acc[r] = bl[lane];

#pragma unroll
    for (int k = 0; k < D; ++k) {
        float wv = Wl[k * D + lane];
#pragma unroll
        for (int r = 0; r < 8; ++r)
            acc[r] = fmaf(rows[(w * 8 + r) * RSTRIDE + k], wv, acc[r]);
    }

#pragma unroll
    for (int r = 0; r < 8; ++r) {
        float v = acc[r] > 0.0f ? acc[r] : 0.0f;
        size_t node = row0 + (size_t)w * 8 + r;
        if (BF16OUT) {
            int p = lane >> 4;
            int cin = lane & 15;
            ((ushort_t*)out_)[(size_t)p * n_nodes * 16 + node * 16 + cin] = f2bf(v);
        } else {
            ((float*)out_)[node * D + lane] = v;
        }
    }
}

extern "C" void kernel_launch(void* const* d_in, const int* in_sizes, int n_in,
                              void* d_out, int out_size, void* d_ws, size_t ws_size,
                              hipStream_t stream) {
    const float* x   = (const float*)d_in[0];
    const int*   src = (const int*)d_in[1];
    const int*   dst = (const int*)d_in[2];
    const float* W1  = (const float*)d_in[3];
    const float* b1  = (const float*)d_in[4];
    const float* W2  = (const float*)d_in[5];
    const float* b2  = (const float*)d_in[6];
    float* out = (float*)d_out;

    const int n_nodes = in_sizes[0] / D;
    const int n_edges = in_sizes[1];
    const int nch = (n_edges + CHSZ - 1) / CHSZ;     // 391
    const int nbs = (n_nodes + NPBS - 1) / NPBS;     // 196

    // workspace: Ab(bf16 slabs) | hb(bf16 slabs) | offs | sstart | total |
    //            hist | tmp | esrc
    ushort_t* Ab     = (ushort_t*)d_ws;                       // n_nodes*64 bf16
    ushort_t* hb     = Ab + (size_t)n_nodes * D;              // n_nodes*64 bf16
    int*      offs   = (int*)(hb + (size_t)n_nodes * D);      // n_nodes+1
    int*      sstart = offs + (n_nodes + 1);                  // nbs+1
    int*      total  = sstart + (nbs + 1);                    // nbs
    int*      hist   = total + nbs;                           // nbs*nch
    unsigned* tmp    = (unsigned*)(hist + (size_t)nbs * nch); // n_edges
    int*      esrc   = (int*)(tmp + n_edges);                 // n_edges

    const int agg_nblk = (n_nodes * 2 + 255) / 256;           // blocks per pass
    const int mlp_blocks = (n_nodes + ROWS_PER_BLOCK - 1) / ROWS_PER_BLOCK;
    const int cvt_blocks = (n_nodes * (D / 4) + 255) / 256;

    // ---- CSR build ----
    to_bf16z<<<cvt_blocks, 256, 0, stream>>>((const float4*)x, (uint2*)hb,
                                             n_nodes * (D / 4), total, nbs,
                                             n_nodes);
    k1_hist<<<nch, 512, 0, stream>>>(dst, hist, total, n_edges, nch, nbs);
    k2c_rowscan<<<nbs, 256, 0, stream>>>(hist, total, sstart, nch, nbs, n_edges);
    k3_scatter<<<nch, 512, 0, stream>>>(src, dst, hist, tmp, n_edges, nch, nbs);
    k4_fine<<<nbs, 512, 0, stream>>>(tmp, sstart, esrc, offs, n_nodes);

    // ---- layer 1: agg(xb slabs) -> Ab slabs; mlp -> hb (bf16 slabs) ----
    gin_agg_slab<<<agg_nblk * NSLAB, 256, 0, stream>>>((const uint4*)hb, offs,
                                                       esrc, (uint4*)Ab,
                                                       n_nodes, agg_nblk);
    gin_mlp<true><<<mlp_blocks, 256, 0, stream>>>((const uint4*)Ab, W1, b1,
                                                  hb, n_nodes);

    // ---- layer 2: agg(h1b slabs) -> Ab slabs; mlp -> out (fp32) ----
    gin_agg_slab<<<agg_nblk * NSLAB, 256, 0, stream>>>((const uint4*)hb, offs,
                                                       esrc, (uint4*)Ab,
                                                       n_nodes, agg_nblk);
    gin_mlp<false><<<mlp_blocks, 256, 0, stream>>>((const uint4*)Ab, W2, b2,
                                                   out, n_nodes);
}

// Round 14
// 184.286 us; speedup vs baseline: 1.3163x; 1.3163x over previous
//
#include <hip/hip_runtime.h>
#include <hip/hip_bf16.h>

// 2-layer GIN, pull-mode aggregation, bf16 feature AND bf16 agg matrices.
//   aggb = bf16( f32(hb[n]) + sum f32(hb[src]) );  h' = relu(agg @ W + b)
// R15 = R12 (best: 186.7us) + two consolidations:
//   - to_bf16 and k1_hist merged into one grid-partitioned dispatch
//   - k4 stages its tmp window in LDS (single global read, guarded fallback)
// R13's 32B slab gathers OVERFETCHED (179MB, half-line granules): gather
// granule must be the full 128B line -> row-major 128B rows are optimal.
// Requires n_nodes <= 131072 (18-bit src pack, 256-bucket scans).

#define D 64
#define ROWS_PER_BLOCK 32
#define CHSZ 4096      // edges per chunk (k1/k3)
#define NPBS 512       // nodes per super-bucket
#define SBSHIFT 9      // log2(NPBS)
#define MAXNBS 256     // static cap on #super-buckets (n_nodes <= 131072)
#define MAXNCH 512     // static cap on #chunks in k2c (n_edges <= 2.1M)
#define SCAP 12288     // k4 LDS edge-staging capacity (48 KB)

typedef unsigned short ushort_t;

__device__ inline unsigned short f2bf(float f) {   // RNE round to bf16
    unsigned u = __float_as_uint(f);
    return (unsigned short)((u + 0x7fff + ((u >> 16) & 1)) >> 16);
}

// acc[0..7] += 8 bf16 unpacked from one uint4
__device__ inline void acc8(float* acc, uint4 v) {
    acc[0] += __uint_as_float(v.x << 16);
    acc[1] += __uint_as_float(v.x & 0xffff0000u);
    acc[2] += __uint_as_float(v.y << 16);
    acc[3] += __uint_as_float(v.y & 0xffff0000u);
    acc[4] += __uint_as_float(v.z << 16);
    acc[5] += __uint_as_float(v.z & 0xffff0000u);
    acc[6] += __uint_as_float(v.w << 16);
    acc[7] += __uint_as_float(v.w & 0xffff0000u);
}

// 8 floats from one uint4 of packed bf16
__device__ inline void unpack8(float* v, uint4 u) {
    v[0] = __uint_as_float(u.x << 16); v[1] = __uint_as_float(u.x & 0xffff0000u);
    v[2] = __uint_as_float(u.y << 16); v[3] = __uint_as_float(u.y & 0xffff0000u);
    v[4] = __uint_as_float(u.z << 16); v[5] = __uint_as_float(u.z & 0xffff0000u);
    v[6] = __uint_as_float(u.w << 16); v[7] = __uint_as_float(u.w & 0xffff0000u);
}

// ---------------- CSR build ----------------

// Merged dispatch: blocks [0, cvtb) do fp32->bf16 conversion (block 0 also
// zeros bucket totals); blocks [cvtb, cvtb+nch) do the per-chunk histogram.
__global__ __launch_bounds__(512) void cvt_hist(const float4* __restrict__ in,
                                                uint2* __restrict__ out, int n4,
                                                const int* __restrict__ dst,
                                                int* __restrict__ hist,
                                                int* __restrict__ total,
                                                int n_edges, int nch, int nbs,
                                                int cvtb) {
    __shared__ int lh[MAXNBS];
    if (blockIdx.x < (unsigned)cvtb) {
        int i = blockIdx.x * 512 + threadIdx.x;
        if (blockIdx.x == 0)
            for (int j = threadIdx.x; j < nbs; j += 512) total[j] = 0;
        if (i < n4) {
            float4 v = in[i];
            out[i] = make_uint2(
                (unsigned)f2bf(v.x) | ((unsigned)f2bf(v.y) << 16),
                (unsigned)f2bf(v.z) | ((unsigned)f2bf(v.w) << 16));
        }
        return;
    }
    int c = blockIdx.x - cvtb;
    for (int i = threadIdx.x; i < nbs; i += 512) lh[i] = 0;
    __syncthreads();
    int base = c * CHSZ;
    int lim = min(CHSZ, n_edges - base);
    for (int k = threadIdx.x; k < lim; k += 512)
        atomicAdd(&lh[dst[base + k] >> SBSHIFT], 1);
    __syncthreads();
    for (int i = threadIdx.x; i < nbs; i += 512) {
        int v = lh[i];
        hist[i * nch + c] = v;   // bucket-major
        if (v) atomicAdd(&total[i], v);
    }
}

// One block per bucket: totals prefix (k2b folded) + row scan, in place.
__global__ __launch_bounds__(256) void k2c_rowscan(int* __restrict__ hist,
                                                   const int* __restrict__ total,
                                                   int* __restrict__ sstart,
                                                   int nch, int nbs, int n_edges) {
    __shared__ int tt[256];
    __shared__ int t[MAXNCH];
    int b = blockIdx.x;
    int tid = threadIdx.x;

    tt[tid] = (tid < nbs) ? total[tid] : 0;
    __syncthreads();
    for (int off = 1; off < 256; off <<= 1) {
        int v = (tid >= off) ? tt[tid - off] : 0;
        __syncthreads();
        tt[tid] += v;
        __syncthreads();
    }
    int base = (b == 0) ? 0 : tt[b - 1];
    if (tid == 0) {
        sstart[b] = base;
        if (b == 0) sstart[nbs] = n_edges;
    }

    int* row = hist + (size_t)b * nch;
    int nround = (nch + 255) & ~255;
    for (int i = tid; i < nround; i += 256) t[i] = (i < nch) ? row[i] : 0;
    __syncthreads();
    for (int off = 1; off < nround; off <<= 1) {
        int v[MAXNCH / 256];
        for (int i = tid, j = 0; i < nround; i += 256, ++j)
            v[j] = (i >= off) ? t[i - off] : 0;
        __syncthreads();
        for (int i = tid, j = 0; i < nround; i += 256, ++j) t[i] += v[j];
        __syncthreads();
    }
    for (int i = tid; i < nch; i += 256)
        row[i] = base + ((i == 0) ? 0 : t[i - 1]);
}

__global__ __launch_bounds__(512) void k3_scatter(const int* __restrict__ src,
                                                  const int* __restrict__ dst,
                                                  const int* __restrict__ hist,
                                                  unsigned* __restrict__ tmp,
                                                  int n_edges, int nch, int nbs) {
    __shared__ int lcur[MAXNBS];
    int c = blockIdx.x;
    for (int i = threadIdx.x; i < nbs; i += 512) lcur[i] = hist[i * nch + c];
    __syncthreads();
    int base = c * CHSZ;
    int lim = min(CHSZ, n_edges - base);
    for (int k = threadIdx.x; k < lim; k += 512) {
        int d = dst[base + k];
        int s = src[base + k];
        int pos = atomicAdd(&lcur[d >> SBSHIFT], 1);
        tmp[pos] = ((unsigned)(d & (NPBS - 1)) << 18) | (unsigned)s;
    }
}

// One WG (512 thr) per super-bucket: node-level counting sort in a WG-owned
// window. tmp window staged in LDS (one global read). esrc PRE-SCALED:
// value = src * 8 (uint4 index of the row base).
__global__ __launch_bounds__(512) void k4_fine(const unsigned* __restrict__ tmp,
                                               const int* __restrict__ sstart,
                                               int* __restrict__ esrc,
                                               int* __restrict__ offs,
                                               int n_nodes) {
    __shared__ int lcnt[NPBS];
    __shared__ int lcur[NPBS];
    __shared__ int tsum[256];
    __shared__ unsigned ledge[SCAP];

    int b = blockIdx.x;
    int tid = threadIdx.x;
    int base = sstart[b];
    int cnt = sstart[b + 1] - base;
    bool fits = (cnt <= SCAP);

    lcnt[tid] = 0;
    __syncthreads();

    if (fits) {
        for (int i = tid; i < cnt; i += 512) {
            unsigned p = tmp[base + i];
            ledge[i] = p;
            atomicAdd(&lcnt[p >> 18], 1);
        }
    } else {
        for (int i = tid; i < cnt; i += 512)
            atomicAdd(&lcnt[tmp[base + i] >> 18], 1);
    }
    __syncthreads();

    // pair-based exclusive scan of 512 counts by the first 256 threads
    int a0 = 0, a1 = 0;
    if (tid < 256) {
        a0 = lcnt[2 * tid];
        a1 = lcnt[2 * tid + 1];
        tsum[tid] = a0 + a1;
    }
    __syncthreads();
    for (int off = 1; off < 256; off <<= 1) {
        int v = 0;
        if (tid < 256 && tid >= off) v = tsum[tid - off];
        __syncthreads();
        if (tid < 256) tsum[tid] += v;
        __syncthreads();
    }
    if (tid < 256) {
        int ex = (tid == 0) ? 0 : tsum[tid - 1];
        lcur[2 * tid] = ex;
        lcur[2 * tid + 1] = ex + a0;
        int node = b * NPBS + 2 * tid;
        if (node <= n_nodes) offs[node] = base + ex;
        if (node + 1 <= n_nodes) offs[node + 1] = base + ex + a0;
    }
    __syncthreads();

    if (fits) {
        for (int i = tid; i < cnt; i += 512) {
            unsigned p = ledge[i];
            int pos = atomicAdd(&lcur[p >> 18], 1);
            esrc[base + pos] = (int)((p & 0x3FFFFu) << 3);   // src*8
        }
    } else {
        for (int i = tid; i < cnt; i += 512) {
            unsigned p = tmp[base + i];
            int pos = atomicAdd(&lcur[p >> 18], 1);
            esrc[base + pos] = (int)((p & 0x3FFFFu) << 3);   // src*8
        }
    }
}

// ---------------- per-layer kernels ----------------

// Pull aggregation over bf16 matrix: 4 lanes/node, lane c owns bf16 cols
// [c*16, c*16+16) = 2 uint4. Edge loop unrolled 8x (16 uint4 in flight).
// acc starts at hb[n] (self term, eps=0). Output agg is bf16.
__global__ __launch_bounds__(128) void gin_agg_bf(const uint4* __restrict__ hb,
                                                  const int* __restrict__ offs,
                                                  const int* __restrict__ esrc,
                                                  uint4* __restrict__ aggb,
                                                  int n_nodes) {
    int t = blockIdx.x * 128 + threadIdx.x;
    int n = t >> 2;
    if (n >= n_nodes) return;
    int c2 = (t & 3) * 2;
    const uint4* selfp = hb + (size_t)n * 8 + c2;   // row = 8 uint4 (128 B)
    float acc[16];
#pragma unroll
    for (int j = 0; j < 16; ++j) acc[j] = 0.0f;
    {
        uint4 s0 = selfp[0], s1 = selfp[1];
        acc8(acc, s0); acc8(acc + 8, s1);
    }

    int i = offs[n];
    int end = offs[n + 1];

    for (; i + 8 <= end; i += 8) {
        uint4 v[16];
#pragma unroll
        for (int j = 0; j < 8; ++j) {
            const uint4* r = hb + (size_t)(unsigned)esrc[i + j] + c2;
            v[2 * j]     = r[0];
            v[2 * j + 1] = r[1];
        }
#pragma unroll
        for (int j = 0; j < 8; ++j) {
            acc8(acc, v[2 * j]);
            acc8(acc + 8, v[2 * j + 1]);
        }
    }
    if (i + 4 <= end) {
        uint4 v[8];
#pragma unroll
        for (int j = 0; j < 4; ++j) {
            const uint4* r = hb + (size_t)(unsigned)esrc[i + j] + c2;
            v[2 * j]     = r[0];
            v[2 * j + 1] = r[1];
        }
#pragma unroll
        for (int j = 0; j < 4; ++j) {
            acc8(acc, v[2 * j]);
            acc8(acc + 8, v[2 * j + 1]);
        }
        i += 4;
    }
    for (; i < end; ++i) {
        const uint4* r = hb + (size_t)(unsigned)esrc[i] + c2;
        uint4 a = r[0], b = r[1];
        acc8(acc, a); acc8(acc + 8, b);
    }

    uint4 o0, o1;
    o0.x = (unsigned)f2bf(acc[0])  | ((unsigned)f2bf(acc[1])  << 16);
    o0.y = (unsigned)f2bf(acc[2])  | ((unsigned)f2bf(acc[3])  << 16);
    o0.z = (unsigned)f2bf(acc[4])  | ((unsigned)f2bf(acc[5])  << 16);
    o0.w = (unsigned)f2bf(acc[6])  | ((unsigned)f2bf(acc[7])  << 16);
    o1.x = (unsigned)f2bf(acc[8])  | ((unsigned)f2bf(acc[9])  << 16);
    o1.y = (unsigned)f2bf(acc[10]) | ((unsigned)f2bf(acc[11]) << 16);
    o1.z = (unsigned)f2bf(acc[12]) | ((unsigned)f2bf(acc[13]) << 16);
    o1.w = (unsigned)f2bf(acc[14]) | ((unsigned)f2bf(acc[15]) << 16);
    aggb[(size_t)n * 8 + c2]     = o0;
    aggb[(size_t)n * 8 + c2 + 1] = o1;
}

// out = relu(hs @ W + b); hs is bf16 (uint4-packed), staged to fp32 LDS.
#define RSTRIDE (D + 4)   // padded LDS row stride (bank-spread)
template <bool BF16OUT>
__global__ __launch_bounds__(256) void gin_mlp(const uint4* __restrict__ hs,
                                               const float* __restrict__ W,
                                               const float* __restrict__ b,
                                               void* __restrict__ out_,
                                               int n_nodes) {
    __shared__ float Wl[D * D];
    __shared__ float bl[D];
    __shared__ float rows[ROWS_PER_BLOCK * RSTRIDE];

    int tid = threadIdx.x;

    const float4* W4 = (const float4*)W;
    float4* Wl4 = (float4*)Wl;
#pragma unroll
    for (int i = 0; i < 4; ++i) Wl4[tid + 256 * i] = W4[tid + 256 * i];
    if (tid < D / 4) ((float4*)bl)[tid] = ((const float4*)b)[tid];

    // stage 32 bf16 rows -> fp32 LDS (1 uint4 = 8 elems per thread)
    size_t row0 = (size_t)blockIdx.x * ROWS_PER_BLOCK;
    {
        uint4 u = hs[row0 * 8 + tid];
        float v[8];
        unpack8(v, u);
        int r = tid >> 3;            // 8 uint4 per 64-col row
        int col = (tid & 7) * 8;
        float* dstp = rows + r * RSTRIDE + col;
#pragma unroll
        for (int j = 0; j < 8; ++j) dstp[j] = v[j];
    }
    __syncthreads();

    int lane = tid & 63;
    int w = tid >> 6;

    float acc[8];
#pragma unroll
    for (int r = 0; r < 8; ++r) acc[r] = bl[lane];

#pragma unroll
    for (int k = 0; k < D; ++k) {
        float wv = Wl[k * D + lane];
#pragma unroll
        for (int r = 0; r < 8; ++r)
            acc[r] = fmaf(rows[(w * 8 + r) * RSTRIDE + k], wv, acc[r]);
    }

#pragma unroll
    for (int r = 0; r < 8; ++r) {
        float v = acc[r] > 0.0f ? acc[r] : 0.0f;
        size_t idx = (row0 + (size_t)w * 8 + r) * D + lane;
        if (BF16OUT) ((ushort_t*)out_)[idx] = f2bf(v);
        else         ((float*)out_)[idx] = v;
    }
}

extern "C" void kernel_launch(void* const* d_in, const int* in_sizes, int n_in,
                              void* d_out, int out_size, void* d_ws, size_t ws_size,
                              hipStream_t stream) {
    const float* x   = (const float*)d_in[0];
    const int*   src = (const int*)d_in[1];
    const int*   dst = (const int*)d_in[2];
    const float* W1  = (const float*)d_in[3];
    const float* b1  = (const float*)d_in[4];
    const float* W2  = (const float*)d_in[5];
    const float* b2  = (const float*)d_in[6];
    float* out = (float*)d_out;

    const int n_nodes = in_sizes[0] / D;
    const int n_edges = in_sizes[1];
    const int nch = (n_edges + CHSZ - 1) / CHSZ;     // 391
    const int nbs = (n_nodes + NPBS - 1) / NPBS;     // 196

    // workspace: Ab(bf16) | hb(bf16) | offs | sstart | total | hist | tmp | esrc
    ushort_t* Ab     = (ushort_t*)d_ws;                       // n_nodes*64 bf16
    ushort_t* hb     = Ab + (size_t)n_nodes * D;              // n_nodes*64 bf16
    int*      offs   = (int*)(hb + (size_t)n_nodes * D);      // n_nodes+1
    int*      sstart = offs + (n_nodes + 1);                  // nbs+1
    int*      total  = sstart + (nbs + 1);                    // nbs
    int*      hist   = total + nbs;                           // nbs*nch
    unsigned* tmp    = (unsigned*)(hist + (size_t)nbs * nch); // n_edges
    int*      esrc   = (int*)(tmp + n_edges);                 // n_edges

    const int agg_blocks = (n_nodes * 4 + 127) / 128;
    const int mlp_blocks = (n_nodes + ROWS_PER_BLOCK - 1) / ROWS_PER_BLOCK;
    const int n4 = n_nodes * (D / 4);
    const int cvtb = (n4 + 511) / 512;

    // ---- CSR build (merged cvt+hist; 8 dispatches total this launch) ----
    cvt_hist<<<cvtb + nch, 512, 0, stream>>>((const float4*)x, (uint2*)hb, n4,
                                             dst, hist, total, n_edges, nch,
                                             nbs, cvtb);
    k2c_rowscan<<<nbs, 256, 0, stream>>>(hist, total, sstart, nch, nbs, n_edges);
    k3_scatter<<<nch, 512, 0, stream>>>(src, dst, hist, tmp, n_edges, nch, nbs);
    k4_fine<<<nbs, 512, 0, stream>>>(tmp, sstart, esrc, offs, n_nodes);

    // ---- layer 1: agg(xb) -> Ab; mlp(Ab) -> hb (bf16 h1) ----
    gin_agg_bf<<<agg_blocks, 128, 0, stream>>>((const uint4*)hb, offs, esrc,
                                               (uint4*)Ab, n_nodes);
    gin_mlp<true><<<mlp_blocks, 256, 0, stream>>>((const uint4*)Ab, W1, b1,
                                                  hb, n_nodes);

    // ---- layer 2: agg(h1b) -> Ab; mlp(Ab) -> out (fp32) ----
    gin_agg_bf<<<agg_blocks, 128, 0, stream>>>((const uint4*)hb, offs, esrc,
                                               (uint4*)Ab, n_nodes);
    gin_mlp<false><<<mlp_blocks, 256, 0, stream>>>((const uint4*)Ab, W2, b2,
                                                   out, n_nodes);
}